// Round 2
// baseline (290.061 us; speedup 1.0000x reference)
//
#include <hip/hip_runtime.h>

#define OUT_H 7
#define OUT_W 7
#define FEAT_H 200
#define FEAT_W 200
#define TILE 32

// ---------------- Kernel 1: NCHW -> NHWC transpose ----------------
// Treat each batch as a (C, HW) matrix, produce (HW, C). 32x32 tiles via LDS,
// coalesced on both read (along hw) and write (along c).
__global__ __launch_bounds__(256) void nchw_to_nhwc(
    const float* __restrict__ in,   // (B, C, HW)
    float* __restrict__ out,        // (B, HW, C)
    int C, int HW)
{
    __shared__ float tile[TILE][TILE + 1];
    int hw0 = blockIdx.x * TILE;
    int c0  = blockIdx.y * TILE;
    int b   = blockIdx.z;
    const float* inb = in + (size_t)b * C * HW;
    float* outb      = out + (size_t)b * HW * C;
    int tx = threadIdx.x, ty = threadIdx.y;   // 32 x 8

#pragma unroll
    for (int i = 0; i < 4; ++i) {
        int c  = c0 + ty + i * 8;
        int hw = hw0 + tx;
        if (c < C && hw < HW)
            tile[ty + i * 8][tx] = inb[(size_t)c * HW + hw];
    }
    __syncthreads();
#pragma unroll
    for (int i = 0; i < 4; ++i) {
        int hw = hw0 + ty + i * 8;
        int c  = c0 + tx;
        if (c < C && hw < HW)
            outb[(size_t)hw * C + c] = tile[tx][ty + i * 8];
    }
}

// ---------------- Kernel 2: RoIAlign on NHWC ----------------
// One workgroup per roi; lane = channel. Corner reads are contiguous across C
// (fully coalesced). Results staged in LDS in (c,p) order == output flat order,
// then written out coalesced.
__global__ __launch_bounds__(256) void roialign_nhwc(
    const float* __restrict__ featT,  // (B, HW, C)
    const int*   __restrict__ rois,   // (N, 5)
    float*       __restrict__ out,    // (N, C, 49)
    int C)
{
    __shared__ float acc[256 * OUT_H * OUT_W];   // 49 KB
    const int H = FEAT_H, W = FEAT_W;
    int n = blockIdx.x;
    int c = threadIdx.x;

    const int* r = rois + n * 5;
    int   b   = r[0];
    float x1f = (float)r[1];
    float y1f = (float)r[2];
    float dx  = (float)r[3] - x1f;
    float dy  = (float)r[4] - y1f;

    const float* fb = featT + (size_t)b * (H * W) * C + c;

    for (int jy = 0; jy < OUT_H; ++jy) {
        float sy   = y1f + ((float)jy * dy) / (float)(OUT_H - 1);
        float y0fl = floorf(sy);
        float wy   = sy - y0fl;
        int y0  = min(max((int)y0fl, 0), H - 1);
        int y1i = min(y0 + 1, H - 1);
        float omwy = 1.0f - wy;
        const float* row0 = fb + (size_t)(y0  * W) * C;
        const float* row1 = fb + (size_t)(y1i * W) * C;

#pragma unroll
        for (int jx = 0; jx < OUT_W; ++jx) {
            float sx   = x1f + ((float)jx * dx) / (float)(OUT_W - 1);
            float x0fl = floorf(sx);
            float wx   = sx - x0fl;
            int x0  = min(max((int)x0fl, 0), W - 1);
            int x1i = min(x0 + 1, W - 1);
            float omwx = 1.0f - wx;

            float v00 = row0[(size_t)x0  * C];
            float v01 = row0[(size_t)x1i * C];
            float v10 = row1[(size_t)x0  * C];
            float v11 = row1[(size_t)x1i * C];

            acc[c * (OUT_H * OUT_W) + jy * OUT_W + jx] =
                v00 * omwy * omwx + v01 * omwy * wx +
                v10 * wy   * omwx + v11 * wy   * wx;
        }
    }
    __syncthreads();

    float* ob = out + (size_t)n * C * (OUT_H * OUT_W);
    int total = C * OUT_H * OUT_W;
    for (int k = c; k < total; k += blockDim.x)
        ob[k] = acc[k];   // LDS flat order == output flat order
}

// ---------------- Fallback: direct NCHW kernel (ws too small) ----------------
__global__ __launch_bounds__(256) void roialign_direct(
    const float* __restrict__ feat, const int* __restrict__ rois,
    float* __restrict__ out, int C, int total)
{
    int idx = blockIdx.x * blockDim.x + threadIdx.x;
    if (idx >= total) return;
    const int H = FEAT_H, W = FEAT_W;
    int jx = idx % OUT_W;
    int t  = idx / OUT_W;
    int jy = t % OUT_H;
    t /= OUT_H;
    int c = t % C;
    int n = t / C;
    const int* r = rois + n * 5;
    int b = r[0];
    float x1 = (float)r[1], y1 = (float)r[2];
    float x2 = (float)r[3], y2 = (float)r[4];
    float sy = y1 + ((float)jy * (y2 - y1)) / (float)(OUT_H - 1);
    float sx = x1 + ((float)jx * (x2 - x1)) / (float)(OUT_W - 1);
    float y0f = floorf(sy), x0f = floorf(sx);
    float wy = sy - y0f, wx = sx - x0f;
    int y0  = min(max((int)y0f, 0), H - 1);
    int y1i = min(y0 + 1, H - 1);
    int x0  = min(max((int)x0f, 0), W - 1);
    int x1i = min(x0 + 1, W - 1);
    const float* fp = feat + ((size_t)b * C + c) * (size_t)(H * W);
    float v00 = fp[y0  * W + x0 ];
    float v01 = fp[y0  * W + x1i];
    float v10 = fp[y1i * W + x0 ];
    float v11 = fp[y1i * W + x1i];
    float omwy = 1.0f - wy, omwx = 1.0f - wx;
    out[idx] = v00 * omwy * omwx + v01 * omwy * wx
             + v10 * wy   * omwx + v11 * wy   * wx;
}

extern "C" void kernel_launch(void* const* d_in, const int* in_sizes, int n_in,
                              void* d_out, int out_size, void* d_ws, size_t ws_size,
                              hipStream_t stream)
{
    const float* feat = (const float*)d_in[0];
    const int*   rois = (const int*)d_in[1];
    float*       out  = (float*)d_out;

    int N  = in_sizes[1] / 5;                        // 512
    int C  = out_size / (N * OUT_H * OUT_W);         // 256
    int HW = FEAT_H * FEAT_W;                        // 40000
    int B  = in_sizes[0] / (C * HW);                 // 4

    size_t need = (size_t)B * HW * C * sizeof(float);
    if (ws_size >= need && C == 256) {
        float* featT = (float*)d_ws;
        dim3 tgrid((HW + TILE - 1) / TILE, (C + TILE - 1) / TILE, B);
        dim3 tblk(32, 8, 1);
        nchw_to_nhwc<<<tgrid, tblk, 0, stream>>>(feat, featT, C, HW);
        roialign_nhwc<<<N, 256, 0, stream>>>(featT, rois, out, C);
    } else {
        int total = out_size;
        roialign_direct<<<(total + 255) / 256, 256, 0, stream>>>(feat, rois, out, C, total);
    }
}

// Round 3
// 260.778 us; speedup vs baseline: 1.1123x; 1.1123x over previous
//
#include <hip/hip_runtime.h>
#include <hip/hip_bf16.h>
#include <string.h>

#define OUT_H 7
#define OUT_W 7
#define FEAT_H 200
#define FEAT_W 200
#define HWB  64      // hw rows per transpose block
#define LSTR 258     // LDS row stride (floats): even (float2-aligned), conflict-light

__device__ inline unsigned pack2_bf16(float a, float b) {
    __hip_bfloat16 ha = __float2bfloat16(a);
    __hip_bfloat16 hb = __float2bfloat16(b);
    unsigned short ua, ub;
    memcpy(&ua, &ha, 2);
    memcpy(&ub, &hb, 2);
    return (unsigned)ua | ((unsigned)ub << 16);
}

// ---------------- Kernel 1: NCHW fp32 -> NHWC bf16 ----------------
// Block = 64 hw rows x all 256 channels. Reads: 256B/wave contiguous per
// channel row. Writes: 32KB fully contiguous bf16 per block (no stride).
__global__ __launch_bounds__(256) void nchw_to_nhwc_bf16(
    const float* __restrict__ in,        // (B, 256, HW)
    __hip_bfloat16* __restrict__ out,    // (B, HW, 256)
    int HW)
{
    __shared__ float tile[HWB * LSTR];   // [hw][c], ~66 KB
    int hw0 = blockIdx.x * HWB;
    int b   = blockIdx.y;
    const float* inb = in + (size_t)b * 256 * HW;

    int lane = threadIdx.x & 63;
    int wave = threadIdx.x >> 6;         // 0..3, each owns 64 channels
    int hw   = hw0 + lane;

#pragma unroll 8
    for (int cc = 0; cc < 64; ++cc) {
        int c = (wave << 6) + cc;
        tile[lane * LSTR + c] = inb[(size_t)c * HW + hw];
    }
    __syncthreads();

    // 64*256 elements = 16384; as 8192 packed uint writes, 32 iters x 256 thr.
    unsigned* ob = (unsigned*)(out + ((size_t)b * HW + hw0) * 256);
    int t = threadIdx.x;
#pragma unroll 4
    for (int i = 0; i < 32; ++i) {
        int p   = i * 256 + t;           // packed-pair index
        int j2  = p * 2;                 // element index (even)
        int hwr = j2 >> 8;
        int c   = j2 & 255;
        float2 v = *(const float2*)&tile[hwr * LSTR + c];
        ob[p] = pack2_bf16(v.x, v.y);
    }
}

// ---------------- Kernel 2: RoIAlign on NHWC bf16 ----------------
// One workgroup per roi; lane = channel. Corner reads contiguous across C.
__global__ __launch_bounds__(256) void roialign_nhwc_bf16(
    const __hip_bfloat16* __restrict__ featT,  // (B, HW, 256)
    const int*   __restrict__ rois,            // (N, 5)
    float*       __restrict__ out)             // (N, 256, 49)
{
    __shared__ float acc[256 * OUT_H * OUT_W]; // 49 KB
    const int H = FEAT_H, W = FEAT_W;
    int n = blockIdx.x;
    int c = threadIdx.x;

    const int* r = rois + n * 5;
    int   b   = r[0];
    float x1f = (float)r[1];
    float y1f = (float)r[2];
    float dx  = (float)r[3] - x1f;
    float dy  = (float)r[4] - y1f;

    const __hip_bfloat16* fb = featT + (size_t)b * (H * W) * 256 + c;

    for (int jy = 0; jy < OUT_H; ++jy) {
        float sy   = y1f + ((float)jy * dy) / (float)(OUT_H - 1);
        float y0fl = floorf(sy);
        float wy   = sy - y0fl;
        int y0  = min(max((int)y0fl, 0), H - 1);
        int y1i = min(y0 + 1, H - 1);
        float omwy = 1.0f - wy;
        const __hip_bfloat16* row0 = fb + (size_t)(y0  * W) * 256;
        const __hip_bfloat16* row1 = fb + (size_t)(y1i * W) * 256;

#pragma unroll
        for (int jx = 0; jx < OUT_W; ++jx) {
            float sx   = x1f + ((float)jx * dx) / (float)(OUT_W - 1);
            float x0fl = floorf(sx);
            float wx   = sx - x0fl;
            int x0  = min(max((int)x0fl, 0), W - 1);
            int x1i = min(x0 + 1, W - 1);
            float omwx = 1.0f - wx;

            float v00 = __bfloat162float(row0[(size_t)x0  * 256]);
            float v01 = __bfloat162float(row0[(size_t)x1i * 256]);
            float v10 = __bfloat162float(row1[(size_t)x0  * 256]);
            float v11 = __bfloat162float(row1[(size_t)x1i * 256]);

            acc[c * (OUT_H * OUT_W) + jy * OUT_W + jx] =
                v00 * omwy * omwx + v01 * omwy * wx +
                v10 * wy   * omwx + v11 * wy   * wx;
        }
    }
    __syncthreads();

    float* ob = out + (size_t)n * 256 * (OUT_H * OUT_W);
    int total = 256 * OUT_H * OUT_W;
    for (int k = c; k < total; k += blockDim.x)
        ob[k] = acc[k];
}

// ---------------- Fallback: direct NCHW kernel ----------------
__global__ __launch_bounds__(256) void roialign_direct(
    const float* __restrict__ feat, const int* __restrict__ rois,
    float* __restrict__ out, int C, int total)
{
    int idx = blockIdx.x * blockDim.x + threadIdx.x;
    if (idx >= total) return;
    const int H = FEAT_H, W = FEAT_W;
    int jx = idx % OUT_W;
    int t  = idx / OUT_W;
    int jy = t % OUT_H;
    t /= OUT_H;
    int c = t % C;
    int n = t / C;
    const int* r = rois + n * 5;
    int b = r[0];
    float x1 = (float)r[1], y1 = (float)r[2];
    float x2 = (float)r[3], y2 = (float)r[4];
    float sy = y1 + ((float)jy * (y2 - y1)) / (float)(OUT_H - 1);
    float sx = x1 + ((float)jx * (x2 - x1)) / (float)(OUT_W - 1);
    float y0f = floorf(sy), x0f = floorf(sx);
    float wy = sy - y0f, wx = sx - x0f;
    int y0  = min(max((int)y0f, 0), H - 1);
    int y1i = min(y0 + 1, H - 1);
    int x0  = min(max((int)x0f, 0), W - 1);
    int x1i = min(x0 + 1, W - 1);
    const float* fp = feat + ((size_t)b * C + c) * (size_t)(H * W);
    float v00 = fp[y0  * W + x0 ];
    float v01 = fp[y0  * W + x1i];
    float v10 = fp[y1i * W + x0 ];
    float v11 = fp[y1i * W + x1i];
    float omwy = 1.0f - wy, omwx = 1.0f - wx;
    out[idx] = v00 * omwy * omwx + v01 * omwy * wx
             + v10 * wy   * omwx + v11 * wy   * wx;
}

extern "C" void kernel_launch(void* const* d_in, const int* in_sizes, int n_in,
                              void* d_out, int out_size, void* d_ws, size_t ws_size,
                              hipStream_t stream)
{
    const float* feat = (const float*)d_in[0];
    const int*   rois = (const int*)d_in[1];
    float*       out  = (float*)d_out;

    int N  = in_sizes[1] / 5;                        // 512
    int C  = out_size / (N * OUT_H * OUT_W);         // 256
    int HW = FEAT_H * FEAT_W;                        // 40000
    int B  = in_sizes[0] / (C * HW);                 // 4

    size_t need = (size_t)B * HW * C * sizeof(__hip_bfloat16);  // 82 MB
    if (C == 256 && (HW % HWB) == 0 && ws_size >= need) {
        __hip_bfloat16* featT = (__hip_bfloat16*)d_ws;
        dim3 tgrid(HW / HWB, B, 1);
        nchw_to_nhwc_bf16<<<tgrid, 256, 0, stream>>>(feat, featT, HW);
        roialign_nhwc_bf16<<<N, 256, 0, stream>>>(featT, rois, out);
    } else {
        int total = out_size;
        roialign_direct<<<(total + 255) / 256, 256, 0, stream>>>(feat, rois, out, C, total);
    }
}

// Round 5
// 259.921 us; speedup vs baseline: 1.1160x; 1.0033x over previous
//
#include <hip/hip_runtime.h>
#include <hip/hip_bf16.h>
#include <string.h>

#define OUT_H 7
#define OUT_W 7
#define FEAT_H 200
#define FEAT_W 200
#define HW_ALL (FEAT_H * FEAT_W)
#define HWB  32      // hw rows per transpose block
#define LSTR 260     // LDS row stride (floats): rows 16B-aligned (260*4=1040), low conflict

__device__ inline unsigned pack2_bf16(float a, float b) {
    __hip_bfloat16 ha = __float2bfloat16(a);
    __hip_bfloat16 hb = __float2bfloat16(b);
    unsigned short ua, ub;
    memcpy(&ua, &ha, 2);
    memcpy(&ub, &hb, 2);
    return (unsigned)ua | ((unsigned)ub << 16);
}

// ---------------- Kernel 1: NCHW fp32 -> NHWC bf16 (v2) ----------------
// Block = 32 hw x 256 c. Read: float4 per lane (16 B), 8 iters, fully unrolled.
// Write: ds_read_b128 from LDS, pack bf16, uint2 stores, 16 KB contiguous/block.
__global__ __launch_bounds__(256) void nchw_to_nhwc_bf16_v2(
    const float* __restrict__ in,     // (B, 256, HW)
    unsigned*    __restrict__ outu,   // (B, HW, 256) bf16, viewed as uints
    int HW)
{
    __shared__ float tile[HWB * LSTR];   // ~33 KB -> 4 blocks/CU
    int hw0 = blockIdx.x * HWB;
    int b   = blockIdx.y;
    const float* inb = in + (size_t)b * 256 * HW + hw0;

    int lane = threadIdx.x & 63;
    int w    = threadIdx.x >> 6;     // wave 0..3 owns 64 channels
    int cg   = lane >> 3;            // 0..7  (channel sub-group)
    int xq   = lane & 7;             // 0..7  (hw quad: 4*xq)
    int hwr  = xq << 2;

#pragma unroll
    for (int cc = 0; cc < 8; ++cc) {
        int c = (w << 6) + (cc << 3) + cg;
        float4 v = *(const float4*)(inb + (size_t)c * HW + hwr);
        tile[(hwr + 0) * LSTR + c] = v.x;
        tile[(hwr + 1) * LSTR + c] = v.y;
        tile[(hwr + 2) * LSTR + c] = v.z;
        tile[(hwr + 3) * LSTR + c] = v.w;
    }
    __syncthreads();

    // 32*256 f32 -> 2048 uint2 (4 bf16 each); 8 iters x 256 threads.
    uint2* ob = (uint2*)outu + ((size_t)b * HW + hw0) * 64;  // 64 uint2 per pixel
    int t = threadIdx.x;
#pragma unroll
    for (int i = 0; i < 8; ++i) {
        int q2  = (i << 8) + t;          // uint2 index in block
        int hr  = q2 >> 6;               // hw row 0..31
        int c0  = (q2 & 63) << 2;        // channel base (multiple of 4)
        float4 v = *(const float4*)&tile[hr * LSTR + c0];
        uint2 o;
        o.x = pack2_bf16(v.x, v.y);
        o.y = pack2_bf16(v.z, v.w);
        ob[q2] = o;
    }
}

// ---------------- Kernel 2: RoIAlign on NHWC bf16 (v2) ----------------
// Block = 1 roi. Thread t: position group pg = t>>6 (4 positions in flight),
// channel quad cq = t&63 (4 channels via one uint2 load per corner, 8 B/lane).
__global__ __launch_bounds__(256) void roialign_nhwc_v2(
    const uint2* __restrict__ featT2,  // (B, HW, 64) uint2 = 4 bf16 channels
    const int*   __restrict__ rois,    // (N, 5)
    float*       __restrict__ out)     // (N, 256, 49)
{
    __shared__ float acc[256 * OUT_H * OUT_W];   // 49 KB
    const int H = FEAT_H, W = FEAT_W;
    int n = blockIdx.x;
    const int* r = rois + n * 5;
    int   b   = r[0];
    float x1f = (float)r[1];
    float y1f = (float)r[2];
    float dx  = (float)r[3] - x1f;
    float dy  = (float)r[4] - y1f;

    int t  = threadIdx.x;
    int pg = t >> 6;                 // 0..3 (wave-uniform)
    int cq = t & 63;                 // channel quad index
    const uint2* fb = featT2 + (size_t)b * HW_ALL * 64 + cq;

#define BFLO(u) __uint_as_float((u) << 16)
#define BFHI(u) __uint_as_float((u) & 0xffff0000u)

#pragma unroll
    for (int pi = 0; pi < 13; ++pi) {
        int p = (pi << 2) + pg;
        if (p < 49) {
            int jy = p / 7, jx = p % 7;
            float sy = y1f + ((float)jy * dy) / 6.0f;
            float sx = x1f + ((float)jx * dx) / 6.0f;
            float y0fl = floorf(sy), x0fl = floorf(sx);
            float wy = sy - y0fl,    wx = sx - x0fl;
            int y0  = min(max((int)y0fl, 0), H - 1);
            int y1i = min(y0 + 1, H - 1);
            int x0  = min(max((int)x0fl, 0), W - 1);
            int x1i = min(x0 + 1, W - 1);
            float omwy = 1.0f - wy, omwx = 1.0f - wx;
            float w00 = omwy * omwx, w01 = omwy * wx;
            float w10 = wy * omwx,   w11 = wy * wx;

            const uint2* row0 = fb + (size_t)(y0  * W) * 64;
            const uint2* row1 = fb + (size_t)(y1i * W) * 64;
            uint2 u00 = row0[(size_t)x0  * 64];
            uint2 u01 = row0[(size_t)x1i * 64];
            uint2 u10 = row1[(size_t)x0  * 64];
            uint2 u11 = row1[(size_t)x1i * 64];

            float r0 = BFLO(u00.x)*w00 + BFLO(u01.x)*w01 + BFLO(u10.x)*w10 + BFLO(u11.x)*w11;
            float r1 = BFHI(u00.x)*w00 + BFHI(u01.x)*w01 + BFHI(u10.x)*w10 + BFHI(u11.x)*w11;
            float r2 = BFLO(u00.y)*w00 + BFLO(u01.y)*w01 + BFLO(u10.y)*w10 + BFLO(u11.y)*w11;
            float r3 = BFHI(u00.y)*w00 + BFHI(u01.y)*w01 + BFHI(u10.y)*w10 + BFHI(u11.y)*w11;

            int c0 = cq << 2;
            acc[(c0 + 0) * 49 + p] = r0;
            acc[(c0 + 1) * 49 + p] = r1;
            acc[(c0 + 2) * 49 + p] = r2;
            acc[(c0 + 3) * 49 + p] = r3;
        }
    }
    __syncthreads();

    float* ob = out + (size_t)n * (256 * OUT_H * OUT_W);
    for (int k = t; k < 256 * OUT_H * OUT_W; k += 256)
        ob[k] = acc[k];   // LDS flat order == output flat order
}

// ---------------- Fallback: direct NCHW kernel ----------------
__global__ __launch_bounds__(256) void roialign_direct(
    const float* __restrict__ feat, const int* __restrict__ rois,
    float* __restrict__ out, int C, int total)
{
    int idx = blockIdx.x * blockDim.x + threadIdx.x;
    if (idx >= total) return;
    const int H = FEAT_H, W = FEAT_W;
    int jx = idx % OUT_W;
    int t  = idx / OUT_W;
    int jy = t % OUT_H;
    t /= OUT_H;
    int c = t % C;
    int n = t / C;
    const int* r = rois + n * 5;
    int b = r[0];
    float x1 = (float)r[1], y1 = (float)r[2];
    float x2 = (float)r[3], y2 = (float)r[4];
    float sy = y1 + ((float)jy * (y2 - y1)) / (float)(OUT_H - 1);
    float sx = x1 + ((float)jx * (x2 - x1)) / (float)(OUT_W - 1);
    float y0f = floorf(sy), x0f = floorf(sx);
    float wy = sy - y0f, wx = sx - x0f;
    int y0  = min(max((int)y0f, 0), H - 1);
    int y1i = min(y0 + 1, H - 1);
    int x0  = min(max((int)x0f, 0), W - 1);
    int x1i = min(x0 + 1, W - 1);
    const float* fp = feat + ((size_t)b * C + c) * (size_t)(H * W);
    float v00 = fp[y0  * W + x0 ];
    float v01 = fp[y0  * W + x1i];
    float v10 = fp[y1i * W + x0 ];
    float v11 = fp[y1i * W + x1i];
    float omwy = 1.0f - wy, omwx = 1.0f - wx;
    out[idx] = v00 * omwy * omwx + v01 * omwy * wx
             + v10 * wy   * omwx + v11 * wy   * wx;
}

extern "C" void kernel_launch(void* const* d_in, const int* in_sizes, int n_in,
                              void* d_out, int out_size, void* d_ws, size_t ws_size,
                              hipStream_t stream)
{
    const float* feat = (const float*)d_in[0];
    const int*   rois = (const int*)d_in[1];
    float*       out  = (float*)d_out;

    int N  = in_sizes[1] / 5;                        // 512
    int C  = out_size / (N * OUT_H * OUT_W);         // 256
    int HW = FEAT_H * FEAT_W;                        // 40000
    int B  = in_sizes[0] / (C * HW);                 // 4

    size_t need = (size_t)B * HW * C * sizeof(__hip_bfloat16);  // 82 MB
    if (C == 256 && (HW % HWB) == 0 && ws_size >= need) {
        unsigned* featT = (unsigned*)d_ws;
        dim3 tgrid(HW / HWB, B, 1);
        nchw_to_nhwc_bf16_v2<<<tgrid, 256, 0, stream>>>(feat, featT, HW);
        roialign_nhwc_v2<<<N, 256, 0, stream>>>((const uint2*)featT, rois, out);
    } else {
        int total = out_size;
        roialign_direct<<<(total + 255) / 256, 256, 0, stream>>>(feat, rois, out, C, total);
    }
}